// Round 1
// 571.941 us; speedup vs baseline: 1.0673x; 1.0673x over previous
//
#include <hip/hip_runtime.h>
#include <math.h>

#define MAX_LEN 4096
#define D_MODEL 768
#define PE_DIM 65
#define MLP_W 64
#define NBATCH 4
#define D3 2304               // (ORDER+1)*D_MODEL
#define ROWS (NBATCH*MAX_LEN) // 16384

typedef unsigned short u16;
typedef unsigned int u32;
typedef float f4 __attribute__((ext_vector_type(4)));
typedef __bf16 bf16x8 __attribute__((ext_vector_type(8)));
typedef float f32x4 __attribute__((ext_vector_type(4)));

__device__ inline u16 f2bf(float x) {
    u32 u = __float_as_uint(x);
    u += 0x7fffu + ((u >> 16) & 1u);   // round-to-nearest-even
    return (u16)(u >> 16);
}
__device__ inline float bf2f(u16 v) { return __uint_as_float((u32)v << 16); }
__device__ inline u32 pk2(float a, float b) {
    return (u32)f2bf(a) | ((u32)f2bf(b) << 16);
}

// direct global->LDS async copy, 16B per lane; lds base must be wave-uniform.
// One call moves 64 lanes x 16B = 1KB, landing at ldsbase + lane*16B.
#define GLDS16(gp, lp) __builtin_amdgcn_global_load_lds( \
    (const __attribute__((address_space(1))) u32*)(gp), \
    (__attribute__((address_space(3))) u32*)(lp), 16, 0, 0)

// ---------------------------------------------------------------------------
// K1: filter MLP + decay -> hTt (MAX_LEN x D_MODEL, t-major, coalesced writes)
// ---------------------------------------------------------------------------
__global__ void filter_kernel(const float* __restrict__ z,
                              const float* __restrict__ fin_W,
                              const float* __restrict__ fin_b,
                              const float* __restrict__ freq,
                              const float* __restrict__ mid_W,
                              const float* __restrict__ mid_b,
                              const float* __restrict__ fout_W,
                              float* __restrict__ hTt)
{
    int t = blockIdx.x;
    int j = threadIdx.x;  // 0..63
    __shared__ float zrow[PE_DIM];
    __shared__ float k1[MLP_W];
    __shared__ float k2[MLP_W];
    __shared__ float k3[MLP_W];
    for (int i = j; i < PE_DIM; i += MLP_W) zrow[i] = z[t*PE_DIM + i];
    __syncthreads();
    float fj = freq[j];
    float acc = fin_b[j];
    for (int i = 0; i < PE_DIM; ++i) acc += zrow[i]*fin_W[i*MLP_W + j];
    k1[j] = sinf(fj*acc);
    __syncthreads();
    acc = mid_b[j];
    for (int i = 0; i < MLP_W; ++i) acc += k1[i]*mid_W[i*MLP_W + j];
    k2[j] = sinf(fj*acc);
    __syncthreads();
    acc = mid_b[MLP_W + j];
    for (int i = 0; i < MLP_W; ++i) acc += k2[i]*mid_W[MLP_W*MLP_W + i*MLP_W + j];
    k3[j] = sinf(fj*acc);
    __syncthreads();
    const float MIND = -3.0701134573253944f;   // ln(0.01)/1.5
    const float MAXD = -15.350567286626972f;   // ln(0.01)/0.3
    float tt = (float)t * (1.0f/(float)(MAX_LEN-1));
    for (int m = 0; m < D_MODEL/MLP_W; ++m) {
        int d = j + MLP_W*m;
        float a = 0.f;
        for (int i = 0; i < MLP_W; ++i) a += k3[i]*fout_W[i*D_MODEL + d];
        float delta = MIND + (MAXD-MIND)*((float)d*(1.0f/(float)(D_MODEL-1)));
        float dec = expf(-tt*fabsf(delta));
        hTt[(size_t)t*D_MODEL + d] = a*dec;   // coalesced
    }
}

// ---------------------------------------------------------------------------
// cast fp32 -> bf16 (elementwise, 8/thread)
// ---------------------------------------------------------------------------
__global__ void cast_bf16_kernel(const float* __restrict__ src,
                                 u16* __restrict__ dst, int n)
{
    int i = (blockIdx.x*256 + threadIdx.x)*8;
    if (i + 7 >= n) {
        for (int j = i; j < n; ++j) dst[j] = f2bf(src[j]);
        return;
    }
    float4 a = *(const float4*)(src + i);
    float4 b = *(const float4*)(src + i + 4);
    uint4 o;
    o.x = pk2(a.x, a.y);
    o.y = pk2(a.z, a.w);
    o.z = pk2(b.x, b.y);
    o.w = pk2(b.z, b.w);
    *(uint4*)(dst + i) = o;
}

// ---------------------------------------------------------------------------
// transpose + cast: src (R x C fp32) -> dst (C x R bf16)
// ---------------------------------------------------------------------------
__global__ void transpose_cast_kernel(const float* __restrict__ src,
                                      u16* __restrict__ dst, int R, int C)
{
    __shared__ u16 tile[64][65];
    int c0 = blockIdx.x*64, r0 = blockIdx.y*64;
    int tid = threadIdx.x;
    #pragma unroll
    for (int p = 0; p < 16; ++p) {
        int idx = tid + 256*p;
        int rr = idx >> 6, cc = idx & 63;
        tile[rr][cc] = f2bf(src[(size_t)(r0+rr)*C + c0 + cc]);
    }
    __syncthreads();
    #pragma unroll
    for (int p = 0; p < 16; ++p) {
        int idx = tid + 256*p;
        int cr = idx >> 6, rc = idx & 63;
        dst[(size_t)(c0+cr)*R + r0 + rc] = tile[rc][cr];
    }
}

// ---------------------------------------------------------------------------
// K2/K6: C[M,N] = A[M,K]bf16 @ Bt[N,K]bf16 + bias
// m97 structure: 128x128 tile, BK=32, global_load_lds width=16, unpadded
// 32-u16 LDS rows, 2 barriers/iter, 4x4 MFMA 16x16x32 per wave.
// ---------------------------------------------------------------------------
__launch_bounds__(256)
__global__ void gemm_mfma_kernel(const u16* __restrict__ A,   // M x K
                                 const u16* __restrict__ Bt,  // N x K
                                 const float* __restrict__ bias,
                                 float* __restrict__ C,
                                 int M, int N, int K)
{
    __shared__ __align__(16) u16 As[128*32];
    __shared__ __align__(16) u16 Bs[128*32];
    int tid = threadIdx.x;
    int lane = tid & 63, w = tid >> 6;
    int wm = (w >> 1)*64, wn = (w & 1)*64;
    int lrow = lane & 15, lch = lane >> 4;
    int m0 = blockIdx.y * 128, n0 = blockIdx.x * 128;

    int srow = lane >> 2;          // 0..15
    int scol = (lane & 3)*8;
    const u16* Ag = A  + (size_t)(m0 + w*32 + srow)*K + scol;
    const u16* Bg = Bt + (size_t)(n0 + w*32 + srow)*K + scol;
    u16* AsW = As + w*1024;   // wave-uniform
    u16* BsW = Bs + w*1024;

    f32x4 acc[4][4];
    #pragma unroll
    for (int i = 0; i < 4; ++i)
        #pragma unroll
        for (int j = 0; j < 4; ++j)
            acc[i][j] = (f32x4){0.f,0.f,0.f,0.f};

    for (int k0 = 0; k0 < K; k0 += 32) {
        GLDS16(Ag + k0,            AsW);
        GLDS16(Ag + 16*(size_t)K + k0, AsW + 512);
        GLDS16(Bg + k0,            BsW);
        GLDS16(Bg + 16*(size_t)K + k0, BsW + 512);
        __syncthreads();               // drains vmcnt(0): tile visible
        bf16x8 af[4], bfr[4];
        #pragma unroll
        for (int i = 0; i < 4; ++i) {
            af[i]  = *(const bf16x8*)&As[(wm + i*16 + lrow)*32 + lch*8];
            bfr[i] = *(const bf16x8*)&Bs[(wn + i*16 + lrow)*32 + lch*8];
        }
        #pragma unroll
        for (int mt = 0; mt < 4; ++mt)
            #pragma unroll
            for (int nt = 0; nt < 4; ++nt)
                acc[mt][nt] = __builtin_amdgcn_mfma_f32_16x16x32_bf16(
                    af[mt], bfr[nt], acc[mt][nt], 0, 0, 0);
        __syncthreads();               // reads done before next overwrite
    }
    #pragma unroll
    for (int nt = 0; nt < 4; ++nt) {
        int n = n0 + wn + nt*16 + lrow;
        float bv = bias[n];
        #pragma unroll
        for (int mt = 0; mt < 4; ++mt) {
            int m = m0 + wm + mt*16 + lch*4;
            #pragma unroll
            for (int r = 0; r < 4; ++r)
                C[(size_t)(m + r)*N + n] = acc[mt][nt][r] + bv;
        }
    }
}

// ---------------------------------------------------------------------------
// K3: short conv (width 3, causal) + split; seq=x0*v -> bf16 (B,768,L),
// gate=x1 -> fp32 (B*L,768)
// ---------------------------------------------------------------------------
__global__ void convprep_kernel(const float* __restrict__ up,
                                const float* __restrict__ conv_W,
                                const float* __restrict__ conv_b,
                                u16* __restrict__ seqbf,
                                float* __restrict__ gate)
{
    __shared__ float sb[64][65];
    int d0 = blockIdx.x * 64;
    int t0 = blockIdx.y * 64;
    int b  = blockIdx.z;
    int tid = threadIdx.x;
    #pragma unroll
    for (int i = 0; i < 16; ++i) {
        int idx = tid + 256*i;
        int trow = idx >> 6, dcol = idx & 63;
        int t = t0 + trow;
        int d = d0 + dcol;
        size_t r = ((size_t)b*MAX_LEN + t)*D3;
        float uc[3];
        #pragma unroll
        for (int g = 0; g < 3; ++g) {
            int c = d + g*D_MODEL;
            float u0 = up[r + c];
            float u1 = (t >= 1) ? up[r - D3 + c]   : 0.f;
            float u2 = (t >= 2) ? up[r - 2*D3 + c] : 0.f;
            uc[g] = conv_W[c]*u2 + conv_W[D3 + c]*u1 + conv_W[2*D3 + c]*u0 + conv_b[c];
        }
        sb[trow][dcol] = uc[0]*uc[2];
        gate[((size_t)b*MAX_LEN + t)*D_MODEL + d] = uc[1];
    }
    __syncthreads();
    #pragma unroll
    for (int i = 0; i < 16; ++i) {
        int idx = tid + 256*i;
        int drow = idx >> 6, tcol = idx & 63;
        seqbf[((size_t)b*D_MODEL + d0 + drow)*MAX_LEN + t0 + tcol] = f2bf(sb[tcol][drow]);
    }
}

// ---------------------------------------------------------------------------
// K4: long causal depthwise conv via block-Toeplitz MFMA.
// v2: ONE block per d; 4 waves = 4 batches. Round-PAIR blocking: per pair p
// (rounds r0=2p, r1=2p+1) we build 16 Toeplitz slabs once (shared by all 4
// batches), and each B-fragment read feeds TWO MFMAs:
//   B(delta,s) -> acc[delta+2p]   via even-r slab s      (M1)
//   B(delta,s) -> acc[delta+2p+1] via odd-r  slab s+8    (M2)
// LDS b128 reads/MFMA drop ~1.5 -> ~0.65; slab builds amortize 4x.
// B addressing is strength-reduced: swizzled byte offset = base(p,s) + 576*g
// (exact: 32*g quads ≡ 0 mod 8 through the 9/8 swizzle), so the unrolled
// g-loop folds 576*g into the ds_read immediate.
// Slab stride 648 u16 (648*2=1296B ≡ 16B mod 128B) so build writes spread
// across banks (old 640 stride put every slab on the same bank set).
// M1/M2 are software-pipelined in blocks of 4 g's -> dependent-MFMA distance
// >= 4 (old code had 8 back-to-back dependent MFMAs on one acc).
// ---------------------------------------------------------------------------
__launch_bounds__(256)
__global__ void longconv_mfma_kernel(const u16* __restrict__ seqbf, // (B,768,L) bf16
                                     const u16* __restrict__ hbf,   // (768,L) bf16
                                     const float* __restrict__ filt_bias,
                                     float* __restrict__ yT)        // (B,768,L) fp32
{
    __shared__ __align__(16) u16 sq[4*4896];   // per-batch swizzled seq, 256-elem zero pad below
    __shared__ __align__(16) u16 hp[4112];     // bf16 h, 16-elem zero pad below
    __shared__ __align__(16) u16 A_s[16*648];  // 16 slabs (r0: s0..7, r1: s8..15), 16 x 40 u16 used

    int d   = blockIdx.x;
    int tid = threadIdx.x;
    int lane = tid & 63, w = tid >> 6;         // w = batch
    int lrow = lane & 15, lch = lane >> 4;

    // stage seq for all 4 batches (9/8 swizzle expansion) + h (shared per d)
    for (int q = tid; q < 4*544; q += 256) {
        int b = q / 544, qq = q - b*544;       // 32 pad quads + 512 data per batch
        int p = b*4896 + ((qq + (qq >> 3)) << 3);
        uint4 o = make_uint4(0u,0u,0u,0u);
        if (qq >= 32) o = *(const uint4*)&seqbf[((size_t)b*D_MODEL + d)*MAX_LEN + (size_t)(qq-32)*8];
        *(uint4*)&sq[p] = o;
    }
    for (int q = tid; q < 514; q += 256) {     // 2 pad quads + 512 data
        uint4 o = make_uint4(0u,0u,0u,0u);
        if (q >= 2) o = *(const uint4*)&hbf[(size_t)d*MAX_LEN + (size_t)(q-2)*8];
        *(uint4*)&hp[q*8] = o;
    }

    f32x4 acc[16];
    #pragma unroll
    for (int g = 0; g < 16; ++g) acc[g] = (f32x4){0.f,0.f,0.f,0.f};

    // slab build: one thread per (slab, row)
    int slab_b = tid >> 4;                     // 0..15
    int i_b    = tid & 15;
    u32* bld = (u32*)&A_s[slab_b*648 + i_b*40];

    const char* sqb = (const char*)(sq + w*4896);   // per-wave (batch) base
    int Q0 = 30 + 2*lrow + lch;                     // = (240+16lrow+8lch)/8

#define MM(af_, bf_, gi) acc[gi] = __builtin_amdgcn_mfma_f32_16x16x32_bf16(af_, bf_, acc[gi], 0, 0, 0)
#define GB(gb, DO_CARRY)                                                      \
    {                                                                         \
        bf16x8 bc0, bc1, bc2, bc3;                                            \
        if (4*(gb)+0 >= gmin) bc0 = *(const bf16x8*)(bp + 576*(4*(gb)+0));    \
        if (4*(gb)+1 >= gmin) bc1 = *(const bf16x8*)(bp + 576*(4*(gb)+1));    \
        if (4*(gb)+2 >= gmin) bc2 = *(const bf16x8*)(bp + 576*(4*(gb)+2));    \
        if (4*(gb)+3 >= gmin) bc3 = *(const bf16x8*)(bp + 576*(4*(gb)+3));    \
        if (4*(gb)+0 >= gmin) MM(aA, bc0, 4*(gb)+0);                          \
        if (4*(gb)+1 >= gmin) MM(aA, bc1, 4*(gb)+1);                          \
        if (4*(gb)+2 >= gmin) MM(aA, bc2, 4*(gb)+2);                          \
        if (4*(gb)+3 >= gmin) MM(aA, bc3, 4*(gb)+3);                          \
        if ((DO_CARRY) && 4*(gb)-1 >= gmin) MM(aB, bcarry, 4*(gb));           \
        if (4*(gb)+0 >= gmin) MM(aB, bc0, 4*(gb)+1);                          \
        if (4*(gb)+1 >= gmin) MM(aB, bc1, 4*(gb)+2);                          \
        if (4*(gb)+2 >= gmin) MM(aB, bc2, 4*(gb)+3);                          \
        bcarry = bc3;                                                         \
    }

    #pragma unroll 1
    for (int p = 0; p < 8; ++p) {
        __syncthreads();   // prior pair's A_s reads done (and staging on p=0)
        {   // build 16 slabs: slab 0..7 -> r=2p (s=slab), 8..15 -> r=2p+1
            int hbase = 32 + 512*p + 32*slab_b + i_b;
            #pragma unroll
            for (int kk = 0; kk < 16; ++kk) {
                u16 v0 = hp[hbase - 2*kk];
                u16 v1 = hp[hbase - 2*kk - 1];
                bld[kk] = (u32)v0 | ((u32)v1 << 16);
            }
        }
        __syncthreads();
        int gmin = 2*p;
        for (int s = 0; s < 8; ++s) {
            bf16x8 aA = *(const bf16x8*)&A_s[ s   *648 + lrow*40 + lch*8];
            bf16x8 aB = *(const bf16x8*)&A_s[(s+8)*648 + lrow*40 + lch*8];
            int Qs = Q0 - 64*p - 4*s;                      // may be negative
            const char* bp = sqb + (Qs*16 + (Qs >> 3)*16); // arith shift = floor
            bf16x8 bcarry;
            GB(0, 0)
            GB(1, 1)
            GB(2, 1)
            GB(3, 1)
        }
    }
#undef GB
#undef MM

    // epilogue: y = acc + filt_bias[d]*seq ; write fp32 to yT
    float fb = filt_bias[d];
    const u16* sqbu = sq + w*4896;
    float* dsty = yT + ((size_t)w*D_MODEL + d)*MAX_LEN;
    #pragma unroll
    for (int g = 0; g < 16; ++g) {
        int t0 = 256*g + 16*lrow + 4*lch;
        int elem = 256 + t0;                 // multiple of 4; 4 elems in one quad
        int Q = elem >> 3;
        const u16* pv = &sqbu[(((Q + (Q >> 3)) << 3)) | (elem & 7)];
        ushort4 sv = *(const ushort4*)pv;    // 8B aligned
        f4 o;
        o[0] = acc[g][0] + fb*bf2f(sv.x);
        o[1] = acc[g][1] + fb*bf2f(sv.y);
        o[2] = acc[g][2] + fb*bf2f(sv.z);
        o[3] = acc[g][3] + fb*bf2f(sv.w);
        *(f4*)&dsty[t0] = o;
    }
}

// ---------------------------------------------------------------------------
// K5: Afin(bf16)[b*L+t, d] = yT[b,d,t] * gate[b*L+t, d]
// ---------------------------------------------------------------------------
__global__ void gatemul_kernel(const float* __restrict__ yT,
                               const float* __restrict__ gate,
                               u16* __restrict__ Afin)
{
    __shared__ float tb[64][65];
    int d0 = blockIdx.x * 64;
    int t0 = blockIdx.y * 64;
    int b  = blockIdx.z;
    int tid = threadIdx.x;
    #pragma unroll
    for (int i = 0; i < 16; ++i) {
        int idx = tid + 256*i;
        int drow = idx >> 6, tcol = idx & 63;
        tb[drow][tcol] = yT[((size_t)b*D_MODEL + d0 + drow)*MAX_LEN + t0 + tcol];
    }
    __syncthreads();
    #pragma unroll
    for (int i = 0; i < 16; ++i) {
        int idx = tid + 256*i;
        int trow = idx >> 6, dcol = idx & 63;
        size_t r = ((size_t)b*MAX_LEN + t0 + trow)*D_MODEL + d0 + dcol;
        Afin[r] = f2bf(tb[dcol][trow] * gate[r]);
    }
}

// ---------------------------------------------------------------------------
extern "C" void kernel_launch(void* const* d_in, const int* in_sizes, int n_in,
                              void* d_out, int out_size, void* d_ws, size_t ws_size,
                              hipStream_t stream)
{
    (void)in_sizes; (void)n_in; (void)out_size; (void)ws_size;
    const float* u      = (const float*)d_in[0];
    const float* z      = (const float*)d_in[1];
    const float* fin_W  = (const float*)d_in[2];
    const float* fin_b  = (const float*)d_in[3];
    const float* freq   = (const float*)d_in[4];
    const float* mid_W  = (const float*)d_in[5];
    const float* mid_b  = (const float*)d_in[6];
    const float* fout_W = (const float*)d_in[7];
    const float* proj_W = (const float*)d_in[8];
    const float* proj_b = (const float*)d_in[9];
    const float* conv_W = (const float*)d_in[10];
    const float* conv_b = (const float*)d_in[11];
    const float* fbias  = (const float*)d_in[12];
    const float* out_W  = (const float*)d_in[13];
    const float* out_b  = (const float*)d_in[14];
    float* out = (float*)d_out;

    // ws layout (floats), total 65,667,072 f = 262.7 MB:
    float* ws    = (float*)d_ws;
    u16*   hbf   = (u16*)ws;                          // 3,145,728 u16 = 1,572,864 f
    float* up    = ws + 1572864;                      // 37,748,736 f
    float* gate  = up + 37748736;                     // 12,582,912 f
    u16*   seqbf = (u16*)(gate + 12582912);           // 12,582,912 u16 = 6,291,456 f
    u16*   Abf   = (u16*)(gate + 12582912 + 6291456); // 12,582,912 u16 = 6,291,456 f
    u16*   BpT1  = (u16*)(gate + 12582912 + 2*6291456);          // 884,736 f
    u16*   BpT2  = (u16*)(gate + 12582912 + 2*6291456 + 884736); // 294,912 f
    // aliases in regions dead at time of use:
    float* hTt   = up;                    // t-major h; dead before GEMM1 writes up
    float* yT    = up;                    // longconv out; up fp32 dead after convprep
    u16*   Afinbf= (u16*)(up + 16777216); // gatemul out; disjoint from yT (12.58M f)

    filter_kernel<<<MAX_LEN, MLP_W, 0, stream>>>(z, fin_W, fin_b, freq,
                                                 mid_W, mid_b, fout_W, hTt);
    transpose_cast_kernel<<<dim3(D_MODEL/64, MAX_LEN/64), 256, 0, stream>>>(
        hTt, hbf, MAX_LEN, D_MODEL);
    cast_bf16_kernel<<<(ROWS*D_MODEL)/(256*8), 256, 0, stream>>>(u, Abf, ROWS*D_MODEL);
    transpose_cast_kernel<<<dim3(D3/64, D_MODEL/64), 256, 0, stream>>>(
        proj_W, BpT1, D_MODEL, D3);
    gemm_mfma_kernel<<<dim3(D3/128, ROWS/128), 256, 0, stream>>>(
        Abf, BpT1, proj_b, up, ROWS, D3, D_MODEL);
    convprep_kernel<<<dim3(D_MODEL/64, MAX_LEN/64, NBATCH), 256, 0, stream>>>(
        up, conv_W, conv_b, seqbf, gate);
    transpose_cast_kernel<<<dim3(D_MODEL/64, D_MODEL/64), 256, 0, stream>>>(
        out_W, BpT2, D_MODEL, D_MODEL);
    longconv_mfma_kernel<<<D_MODEL, 256, 0, stream>>>(seqbf, hbf, fbias, yT);
    gatemul_kernel<<<dim3(D_MODEL/64, MAX_LEN/64, NBATCH), 256, 0, stream>>>(
        yT, gate, Afinbf);
    gemm_mfma_kernel<<<dim3(D_MODEL/128, ROWS/128), 256, 0, stream>>>(
        Afinbf, BpT2, out_b, out, ROWS, D_MODEL, D_MODEL);
}

// Round 2
// 456.110 us; speedup vs baseline: 1.3384x; 1.2540x over previous
//
#include <hip/hip_runtime.h>
#include <math.h>

#define MAX_LEN 4096
#define D_MODEL 768
#define PE_DIM 65
#define MLP_W 64
#define NBATCH 4
#define D3 2304               // (ORDER+1)*D_MODEL
#define ROWS (NBATCH*MAX_LEN) // 16384

typedef unsigned short u16;
typedef unsigned int u32;
typedef float f4 __attribute__((ext_vector_type(4)));
typedef __bf16 bf16x8 __attribute__((ext_vector_type(8)));
typedef float f32x4 __attribute__((ext_vector_type(4)));

__device__ inline u16 f2bf(float x) {
    u32 u = __float_as_uint(x);
    u += 0x7fffu + ((u >> 16) & 1u);   // round-to-nearest-even
    return (u16)(u >> 16);
}
__device__ inline float bf2f(u16 v) { return __uint_as_float((u32)v << 16); }
__device__ inline u32 pk2(float a, float b) {
    return (u32)f2bf(a) | ((u32)f2bf(b) << 16);
}

// direct global->LDS async copy, 16B per lane; lds base must be wave-uniform.
// One call moves 64 lanes x 16B = 1KB, landing at ldsbase + lane*16B.
#define GLDS16(gp, lp) __builtin_amdgcn_global_load_lds( \
    (const __attribute__((address_space(1))) u32*)(gp), \
    (__attribute__((address_space(3))) u32*)(lp), 16, 0, 0)

// ---------------------------------------------------------------------------
// K1a: 3-layer sin-MLP -> k3 (MAX_LEN x 64 fp32).
// v3: was one 64-thread wave per t reading weights from GLOBAL per MAC
// (latency-bound, 145us, VALUBusy 9.7%). Now 16 t per 256-thread block,
// all weights staged in LDS once; weight reads coalesced, activation reads
// wave-uniform broadcast.
// ---------------------------------------------------------------------------
__launch_bounds__(256)
__global__ void filter_mlp_kernel(const float* __restrict__ z,
                                  const float* __restrict__ fin_W,
                                  const float* __restrict__ fin_b,
                                  const float* __restrict__ freq,
                                  const float* __restrict__ mid_W,
                                  const float* __restrict__ mid_b,
                                  float* __restrict__ k3out)
{
    __shared__ __align__(16) float W1[PE_DIM*MLP_W];    // 16.6 KB
    __shared__ __align__(16) float Wm[2*MLP_W*MLP_W];   // 32 KB
    __shared__ __align__(16) float zs[16*PE_DIM];       // 4.2 KB
    __shared__ __align__(16) float kb[2][16*MLP_W];     // 8 KB
    int tid = threadIdx.x;
    int t0 = blockIdx.x * 16;
    for (int i = tid; i < PE_DIM*MLP_W; i += 256) W1[i] = fin_W[i];
    for (int i = tid; i < 2*MLP_W*MLP_W; i += 256) Wm[i] = mid_W[i];
    for (int i = tid; i < 16*PE_DIM; i += 256) zs[i] = z[(size_t)t0*PE_DIM + i];
    __syncthreads();

    int j = tid & 63, tl = tid >> 6;   // j: output unit, tl: 0..3 (t = tl+4*tt)
    float fj = freq[j];
    float a[4];

    // layer 1: z(65) -> 64, sin
    {
        float fb = fin_b[j];
        #pragma unroll
        for (int tt = 0; tt < 4; ++tt) a[tt] = fb;
        for (int i = 0; i < PE_DIM; ++i) {
            float w = W1[i*MLP_W + j];                   // coalesced
            #pragma unroll
            for (int tt = 0; tt < 4; ++tt)
                a[tt] += zs[(tl + 4*tt)*PE_DIM + i] * w; // broadcast
        }
        #pragma unroll
        for (int tt = 0; tt < 4; ++tt)
            kb[0][(tl + 4*tt)*MLP_W + j] = sinf(fj*a[tt]);
    }
    __syncthreads();
    // layer 2
    {
        float mb = mid_b[j];
        #pragma unroll
        for (int tt = 0; tt < 4; ++tt) a[tt] = mb;
        for (int i = 0; i < MLP_W; ++i) {
            float w = Wm[i*MLP_W + j];
            #pragma unroll
            for (int tt = 0; tt < 4; ++tt)
                a[tt] += kb[0][(tl + 4*tt)*MLP_W + i] * w;
        }
        #pragma unroll
        for (int tt = 0; tt < 4; ++tt)
            kb[1][(tl + 4*tt)*MLP_W + j] = sinf(fj*a[tt]);
    }
    __syncthreads();
    // layer 3 -> global k3
    {
        float mb = mid_b[MLP_W + j];
        #pragma unroll
        for (int tt = 0; tt < 4; ++tt) a[tt] = mb;
        for (int i = 0; i < MLP_W; ++i) {
            float w = Wm[MLP_W*MLP_W + i*MLP_W + j];
            #pragma unroll
            for (int tt = 0; tt < 4; ++tt)
                a[tt] += kb[1][(tl + 4*tt)*MLP_W + i] * w;
        }
        #pragma unroll
        for (int tt = 0; tt < 4; ++tt)
            k3out[(size_t)(t0 + tl + 4*tt)*MLP_W + j] = sinf(fj*a[tt]); // coalesced
    }
}

// ---------------------------------------------------------------------------
// K1b: hTt[t,d] = (k3[t,:] @ fout_W[:,d]) * decay(t,d).
// Tile 64t x 128d per block; k3 tile + fout tile staged in LDS; each thread
// accumulates 8t x 4d in registers with f4 FMAs; decay in epilogue.
// ---------------------------------------------------------------------------
__launch_bounds__(256)
__global__ void filter_out_kernel(const float* __restrict__ k3,
                                  const float* __restrict__ fout_W,
                                  float* __restrict__ hTt)
{
    __shared__ __align__(16) float ks[64*64];    // [t][i] 16 KB
    __shared__ __align__(16) float fs[64*132];   // [i][d] padded, 33.8 KB
    int tid = threadIdx.x;
    int d0 = blockIdx.x * 128;
    int t0 = blockIdx.y * 64;

    for (int q = tid; q < 1024; q += 256)        // 4096 floats of k3 tile
        *(f4*)&ks[q*4] = *(const f4*)&k3[(size_t)t0*MLP_W + q*4];
    for (int q = tid; q < 2048; q += 256) {      // 64 rows x 32 f4 of fout tile
        int i = q >> 5, c = q & 31;
        *(f4*)&fs[i*132 + c*4] = *(const f4*)&fout_W[(size_t)i*D_MODEL + d0 + c*4];
    }
    __syncthreads();

    int c = tid & 31;            // d sub-block: d = d0 + 4c + dd
    int t_base = (tid >> 5)*8;   // 8 t per thread
    f4 acc[8];
    #pragma unroll
    for (int tt = 0; tt < 8; ++tt) acc[tt] = (f4){0.f,0.f,0.f,0.f};

    for (int i = 0; i < MLP_W; ++i) {
        f4 fv = *(const f4*)&fs[i*132 + c*4];
        #pragma unroll
        for (int tt = 0; tt < 8; ++tt) {
            float kv = ks[(t_base + tt)*MLP_W + i];   // 2-way broadcast per wave
            acc[tt][0] += kv * fv[0];
            acc[tt][1] += kv * fv[1];
            acc[tt][2] += kv * fv[2];
            acc[tt][3] += kv * fv[3];
        }
    }

    const float MIND = -3.0701134573253944f;   // ln(0.01)/1.5
    const float MAXD = -15.350567286626972f;   // ln(0.01)/0.3
    #pragma unroll
    for (int tt = 0; tt < 8; ++tt) {
        int t = t0 + t_base + tt;
        float ttf = (float)t * (1.0f/(float)(MAX_LEN-1));
        f4 o;
        #pragma unroll
        for (int dd = 0; dd < 4; ++dd) {
            int d = d0 + 4*c + dd;
            float delta = MIND + (MAXD-MIND)*((float)d*(1.0f/(float)(D_MODEL-1)));
            o[dd] = acc[tt][dd] * expf(-ttf*fabsf(delta));
        }
        *(f4*)&hTt[(size_t)t*D_MODEL + d0 + 4*c] = o;   // coalesced f4
    }
}

// ---------------------------------------------------------------------------
// cast fp32 -> bf16 (elementwise, 8/thread)
// ---------------------------------------------------------------------------
__global__ void cast_bf16_kernel(const float* __restrict__ src,
                                 u16* __restrict__ dst, int n)
{
    int i = (blockIdx.x*256 + threadIdx.x)*8;
    if (i + 7 >= n) {
        for (int j = i; j < n; ++j) dst[j] = f2bf(src[j]);
        return;
    }
    float4 a = *(const float4*)(src + i);
    float4 b = *(const float4*)(src + i + 4);
    uint4 o;
    o.x = pk2(a.x, a.y);
    o.y = pk2(a.z, a.w);
    o.z = pk2(b.x, b.y);
    o.w = pk2(b.z, b.w);
    *(uint4*)(dst + i) = o;
}

// ---------------------------------------------------------------------------
// transpose + cast: src (R x C fp32) -> dst (C x R bf16)
// ---------------------------------------------------------------------------
__global__ void transpose_cast_kernel(const float* __restrict__ src,
                                      u16* __restrict__ dst, int R, int C)
{
    __shared__ u16 tile[64][65];
    int c0 = blockIdx.x*64, r0 = blockIdx.y*64;
    int tid = threadIdx.x;
    #pragma unroll
    for (int p = 0; p < 16; ++p) {
        int idx = tid + 256*p;
        int rr = idx >> 6, cc = idx & 63;
        tile[rr][cc] = f2bf(src[(size_t)(r0+rr)*C + c0 + cc]);
    }
    __syncthreads();
    #pragma unroll
    for (int p = 0; p < 16; ++p) {
        int idx = tid + 256*p;
        int cr = idx >> 6, rc = idx & 63;
        dst[(size_t)(c0+cr)*R + r0 + rc] = tile[rc][cr];
    }
}

// ---------------------------------------------------------------------------
// K2/K6: C[M,N] = A[M,K]bf16 @ Bt[N,K]bf16 + bias
// m97 structure: 128x128 tile, BK=32, global_load_lds width=16, unpadded
// 32-u16 LDS rows, 2 barriers/iter, 4x4 MFMA 16x16x32 per wave.
// ---------------------------------------------------------------------------
__launch_bounds__(256)
__global__ void gemm_mfma_kernel(const u16* __restrict__ A,   // M x K
                                 const u16* __restrict__ Bt,  // N x K
                                 const float* __restrict__ bias,
                                 float* __restrict__ C,
                                 int M, int N, int K)
{
    __shared__ __align__(16) u16 As[128*32];
    __shared__ __align__(16) u16 Bs[128*32];
    int tid = threadIdx.x;
    int lane = tid & 63, w = tid >> 6;
    int wm = (w >> 1)*64, wn = (w & 1)*64;
    int lrow = lane & 15, lch = lane >> 4;
    int m0 = blockIdx.y * 128, n0 = blockIdx.x * 128;

    int srow = lane >> 2;          // 0..15
    int scol = (lane & 3)*8;
    const u16* Ag = A  + (size_t)(m0 + w*32 + srow)*K + scol;
    const u16* Bg = Bt + (size_t)(n0 + w*32 + srow)*K + scol;
    u16* AsW = As + w*1024;   // wave-uniform
    u16* BsW = Bs + w*1024;

    f32x4 acc[4][4];
    #pragma unroll
    for (int i = 0; i < 4; ++i)
        #pragma unroll
        for (int j = 0; j < 4; ++j)
            acc[i][j] = (f32x4){0.f,0.f,0.f,0.f};

    for (int k0 = 0; k0 < K; k0 += 32) {
        GLDS16(Ag + k0,            AsW);
        GLDS16(Ag + 16*(size_t)K + k0, AsW + 512);
        GLDS16(Bg + k0,            BsW);
        GLDS16(Bg + 16*(size_t)K + k0, BsW + 512);
        __syncthreads();               // drains vmcnt(0): tile visible
        bf16x8 af[4], bfr[4];
        #pragma unroll
        for (int i = 0; i < 4; ++i) {
            af[i]  = *(const bf16x8*)&As[(wm + i*16 + lrow)*32 + lch*8];
            bfr[i] = *(const bf16x8*)&Bs[(wn + i*16 + lrow)*32 + lch*8];
        }
        #pragma unroll
        for (int mt = 0; mt < 4; ++mt)
            #pragma unroll
            for (int nt = 0; nt < 4; ++nt)
                acc[mt][nt] = __builtin_amdgcn_mfma_f32_16x16x32_bf16(
                    af[mt], bfr[nt], acc[mt][nt], 0, 0, 0);
        __syncthreads();               // reads done before next overwrite
    }
    #pragma unroll
    for (int nt = 0; nt < 4; ++nt) {
        int n = n0 + wn + nt*16 + lrow;
        float bv = bias[n];
        #pragma unroll
        for (int mt = 0; mt < 4; ++mt) {
            int m = m0 + wm + mt*16 + lch*4;
            #pragma unroll
            for (int r = 0; r < 4; ++r)
                C[(size_t)(m + r)*N + n] = acc[mt][nt][r] + bv;
        }
    }
}

// ---------------------------------------------------------------------------
// K3: short conv (width 3, causal) + split; seq=x0*v -> bf16 (B,768,L),
// gate=x1 -> fp32 (B*L,768)
// ---------------------------------------------------------------------------
__global__ void convprep_kernel(const float* __restrict__ up,
                                const float* __restrict__ conv_W,
                                const float* __restrict__ conv_b,
                                u16* __restrict__ seqbf,
                                float* __restrict__ gate)
{
    __shared__ float sb[64][65];
    int d0 = blockIdx.x * 64;
    int t0 = blockIdx.y * 64;
    int b  = blockIdx.z;
    int tid = threadIdx.x;
    #pragma unroll
    for (int i = 0; i < 16; ++i) {
        int idx = tid + 256*i;
        int trow = idx >> 6, dcol = idx & 63;
        int t = t0 + trow;
        int d = d0 + dcol;
        size_t r = ((size_t)b*MAX_LEN + t)*D3;
        float uc[3];
        #pragma unroll
        for (int g = 0; g < 3; ++g) {
            int c = d + g*D_MODEL;
            float u0 = up[r + c];
            float u1 = (t >= 1) ? up[r - D3 + c]   : 0.f;
            float u2 = (t >= 2) ? up[r - 2*D3 + c] : 0.f;
            uc[g] = conv_W[c]*u2 + conv_W[D3 + c]*u1 + conv_W[2*D3 + c]*u0 + conv_b[c];
        }
        sb[trow][dcol] = uc[0]*uc[2];
        gate[((size_t)b*MAX_LEN + t)*D_MODEL + d] = uc[1];
    }
    __syncthreads();
    #pragma unroll
    for (int i = 0; i < 16; ++i) {
        int idx = tid + 256*i;
        int drow = idx >> 6, tcol = idx & 63;
        seqbf[((size_t)b*D_MODEL + d0 + drow)*MAX_LEN + t0 + tcol] = f2bf(sb[tcol][drow]);
    }
}

// ---------------------------------------------------------------------------
// K4: long causal depthwise conv via block-Toeplitz MFMA.
// ONE block per d; 4 waves = 4 batches. Round-PAIR blocking: per pair p
// (rounds r0=2p, r1=2p+1) we build 16 Toeplitz slabs once (shared by all 4
// batches), and each B-fragment read feeds TWO MFMAs.
// ---------------------------------------------------------------------------
__launch_bounds__(256)
__global__ void longconv_mfma_kernel(const u16* __restrict__ seqbf, // (B,768,L) bf16
                                     const u16* __restrict__ hbf,   // (768,L) bf16
                                     const float* __restrict__ filt_bias,
                                     float* __restrict__ yT)        // (B,768,L) fp32
{
    __shared__ __align__(16) u16 sq[4*4896];   // per-batch swizzled seq, 256-elem zero pad below
    __shared__ __align__(16) u16 hp[4112];     // bf16 h, 16-elem zero pad below
    __shared__ __align__(16) u16 A_s[16*648];  // 16 slabs (r0: s0..7, r1: s8..15), 16 x 40 u16 used

    int d   = blockIdx.x;
    int tid = threadIdx.x;
    int lane = tid & 63, w = tid >> 6;         // w = batch
    int lrow = lane & 15, lch = lane >> 4;

    // stage seq for all 4 batches (9/8 swizzle expansion) + h (shared per d)
    for (int q = tid; q < 4*544; q += 256) {
        int b = q / 544, qq = q - b*544;       // 32 pad quads + 512 data per batch
        int p = b*4896 + ((qq + (qq >> 3)) << 3);
        uint4 o = make_uint4(0u,0u,0u,0u);
        if (qq >= 32) o = *(const uint4*)&seqbf[((size_t)b*D_MODEL + d)*MAX_LEN + (size_t)(qq-32)*8];
        *(uint4*)&sq[p] = o;
    }
    for (int q = tid; q < 514; q += 256) {     // 2 pad quads + 512 data
        uint4 o = make_uint4(0u,0u,0u,0u);
        if (q >= 2) o = *(const uint4*)&hbf[(size_t)d*MAX_LEN + (size_t)(q-2)*8];
        *(uint4*)&hp[q*8] = o;
    }

    f32x4 acc[16];
    #pragma unroll
    for (int g = 0; g < 16; ++g) acc[g] = (f32x4){0.f,0.f,0.f,0.f};

    // slab build: one thread per (slab, row)
    int slab_b = tid >> 4;                     // 0..15
    int i_b    = tid & 15;
    u32* bld = (u32*)&A_s[slab_b*648 + i_b*40];

    const char* sqb = (const char*)(sq + w*4896);   // per-wave (batch) base
    int Q0 = 30 + 2*lrow + lch;                     // = (240+16lrow+8lch)/8

#define MM(af_, bf_, gi) acc[gi] = __builtin_amdgcn_mfma_f32_16x16x32_bf16(af_, bf_, acc[gi], 0, 0, 0)
#define GB(gb, DO_CARRY)                                                      \
    {                                                                         \
        bf16x8 bc0, bc1, bc2, bc3;                                            \
        if (4*(gb)+0 >= gmin) bc0 = *(const bf16x8*)(bp + 576*(4*(gb)+0));    \
        if (4*(gb)+1 >= gmin) bc1 = *(const bf16x8*)(bp + 576*(4*(gb)+1));    \
        if (4*(gb)+2 >= gmin) bc2 = *(const bf16x8*)(bp + 576*(4*(gb)+2));    \
        if (4*(gb)+3 >= gmin) bc3 = *(const bf16x8*)(bp + 576*(4*(gb)+3));    \
        if (4*(gb)+0 >= gmin) MM(aA, bc0, 4*(gb)+0);                          \
        if (4*(gb)+1 >= gmin) MM(aA, bc1, 4*(gb)+1);                          \
        if (4*(gb)+2 >= gmin) MM(aA, bc2, 4*(gb)+2);                          \
        if (4*(gb)+3 >= gmin) MM(aA, bc3, 4*(gb)+3);                          \
        if ((DO_CARRY) && 4*(gb)-1 >= gmin) MM(aB, bcarry, 4*(gb));           \
        if (4*(gb)+0 >= gmin) MM(aB, bc0, 4*(gb)+1);                          \
        if (4*(gb)+1 >= gmin) MM(aB, bc1, 4*(gb)+2);                          \
        if (4*(gb)+2 >= gmin) MM(aB, bc2, 4*(gb)+3);                          \
        bcarry = bc3;                                                         \
    }

    #pragma unroll 1
    for (int p = 0; p < 8; ++p) {
        __syncthreads();   // prior pair's A_s reads done (and staging on p=0)
        {   // build 16 slabs: slab 0..7 -> r=2p (s=slab), 8..15 -> r=2p+1
            int hbase = 32 + 512*p + 32*slab_b + i_b;
            #pragma unroll
            for (int kk = 0; kk < 16; ++kk) {
                u16 v0 = hp[hbase - 2*kk];
                u16 v1 = hp[hbase - 2*kk - 1];
                bld[kk] = (u32)v0 | ((u32)v1 << 16);
            }
        }
        __syncthreads();
        int gmin = 2*p;
        for (int s = 0; s < 8; ++s) {
            bf16x8 aA = *(const bf16x8*)&A_s[ s   *648 + lrow*40 + lch*8];
            bf16x8 aB = *(const bf16x8*)&A_s[(s+8)*648 + lrow*40 + lch*8];
            int Qs = Q0 - 64*p - 4*s;                      // may be negative
            const char* bp = sqb + (Qs*16 + (Qs >> 3)*16); // arith shift = floor
            bf16x8 bcarry;
            GB(0, 0)
            GB(1, 1)
            GB(2, 1)
            GB(3, 1)
        }
    }
#undef GB
#undef MM

    // epilogue: y = acc + filt_bias[d]*seq ; write fp32 to yT
    float fb = filt_bias[d];
    const u16* sqbu = sq + w*4896;
    float* dsty = yT + ((size_t)w*D_MODEL + d)*MAX_LEN;
    #pragma unroll
    for (int g = 0; g < 16; ++g) {
        int t0 = 256*g + 16*lrow + 4*lch;
        int elem = 256 + t0;                 // multiple of 4; 4 elems in one quad
        int Q = elem >> 3;
        const u16* pv = &sqbu[(((Q + (Q >> 3)) << 3)) | (elem & 7)];
        ushort4 sv = *(const ushort4*)pv;    // 8B aligned
        f4 o;
        o[0] = acc[g][0] + fb*bf2f(sv.x);
        o[1] = acc[g][1] + fb*bf2f(sv.y);
        o[2] = acc[g][2] + fb*bf2f(sv.z);
        o[3] = acc[g][3] + fb*bf2f(sv.w);
        *(f4*)&dsty[t0] = o;
    }
}

// ---------------------------------------------------------------------------
// K5: Afin(bf16)[b*L+t, d] = yT[b,d,t] * gate[b*L+t, d]
// ---------------------------------------------------------------------------
__global__ void gatemul_kernel(const float* __restrict__ yT,
                               const float* __restrict__ gate,
                               u16* __restrict__ Afin)
{
    __shared__ float tb[64][65];
    int d0 = blockIdx.x * 64;
    int t0 = blockIdx.y * 64;
    int b  = blockIdx.z;
    int tid = threadIdx.x;
    #pragma unroll
    for (int i = 0; i < 16; ++i) {
        int idx = tid + 256*i;
        int drow = idx >> 6, tcol = idx & 63;
        tb[drow][tcol] = yT[((size_t)b*D_MODEL + d0 + drow)*MAX_LEN + t0 + tcol];
    }
    __syncthreads();
    #pragma unroll
    for (int i = 0; i < 16; ++i) {
        int idx = tid + 256*i;
        int trow = idx >> 6, dcol = idx & 63;
        size_t r = ((size_t)b*MAX_LEN + t0 + trow)*D_MODEL + d0 + dcol;
        Afin[r] = f2bf(tb[dcol][trow] * gate[r]);
    }
}

// ---------------------------------------------------------------------------
extern "C" void kernel_launch(void* const* d_in, const int* in_sizes, int n_in,
                              void* d_out, int out_size, void* d_ws, size_t ws_size,
                              hipStream_t stream)
{
    (void)in_sizes; (void)n_in; (void)out_size; (void)ws_size;
    const float* u      = (const float*)d_in[0];
    const float* z      = (const float*)d_in[1];
    const float* fin_W  = (const float*)d_in[2];
    const float* fin_b  = (const float*)d_in[3];
    const float* freq   = (const float*)d_in[4];
    const float* mid_W  = (const float*)d_in[5];
    const float* mid_b  = (const float*)d_in[6];
    const float* fout_W = (const float*)d_in[7];
    const float* proj_W = (const float*)d_in[8];
    const float* proj_b = (const float*)d_in[9];
    const float* conv_W = (const float*)d_in[10];
    const float* conv_b = (const float*)d_in[11];
    const float* fbias  = (const float*)d_in[12];
    const float* out_W  = (const float*)d_in[13];
    const float* out_b  = (const float*)d_in[14];
    float* out = (float*)d_out;

    // ws layout (floats), total 65,667,072 f = 262.7 MB:
    float* ws    = (float*)d_ws;
    u16*   hbf   = (u16*)ws;                          // 3,145,728 u16 = 1,572,864 f
    float* up    = ws + 1572864;                      // 37,748,736 f
    float* gate  = up + 37748736;                     // 12,582,912 f
    u16*   seqbf = (u16*)(gate + 12582912);           // 12,582,912 u16 = 6,291,456 f
    u16*   Abf   = (u16*)(gate + 12582912 + 6291456); // 12,582,912 u16 = 6,291,456 f
    u16*   BpT1  = (u16*)(gate + 12582912 + 2*6291456);          // 884,736 f
    u16*   BpT2  = (u16*)(gate + 12582912 + 2*6291456 + 884736); // 294,912 f
    // aliases in regions dead at time of use:
    float* hTt   = up;                    // t-major h; dead before GEMM1 writes up
    float* yT    = up;                    // longconv out; up fp32 dead after convprep
    u16*   Afinbf= (u16*)(up + 16777216); // gatemul out; disjoint from yT (12.58M f)
    float* k3buf = gate;                  // 1 MB; gate region dead until convprep

    filter_mlp_kernel<<<MAX_LEN/16, 256, 0, stream>>>(z, fin_W, fin_b, freq,
                                                      mid_W, mid_b, k3buf);
    filter_out_kernel<<<dim3(D_MODEL/128, MAX_LEN/64), 256, 0, stream>>>(
        k3buf, fout_W, hTt);
    transpose_cast_kernel<<<dim3(D_MODEL/64, MAX_LEN/64), 256, 0, stream>>>(
        hTt, hbf, MAX_LEN, D_MODEL);
    cast_bf16_kernel<<<(ROWS*D_MODEL)/(256*8), 256, 0, stream>>>(u, Abf, ROWS*D_MODEL);
    transpose_cast_kernel<<<dim3(D3/64, D_MODEL/64), 256, 0, stream>>>(
        proj_W, BpT1, D_MODEL, D3);
    gemm_mfma_kernel<<<dim3(D3/128, ROWS/128), 256, 0, stream>>>(
        Abf, BpT1, proj_b, up, ROWS, D3, D_MODEL);
    convprep_kernel<<<dim3(D_MODEL/64, MAX_LEN/64, NBATCH), 256, 0, stream>>>(
        up, conv_W, conv_b, seqbf, gate);
    transpose_cast_kernel<<<dim3(D_MODEL/64, D_MODEL/64), 256, 0, stream>>>(
        out_W, BpT2, D_MODEL, D_MODEL);
    longconv_mfma_kernel<<<D_MODEL, 256, 0, stream>>>(seqbf, hbf, fbias, yT);
    gatemul_kernel<<<dim3(D_MODEL/64, MAX_LEN/64, NBATCH), 256, 0, stream>>>(
        yT, gate, Afinbf);
    gemm_mfma_kernel<<<dim3(D_MODEL/128, ROWS/128), 256, 0, stream>>>(
        Afinbf, BpT2, out_b, out, ROWS, D_MODEL, D_MODEL);
}

// Round 3
// 401.692 us; speedup vs baseline: 1.5197x; 1.1355x over previous
//
#include <hip/hip_runtime.h>
#include <math.h>

#define MAX_LEN 4096
#define D_MODEL 768
#define PE_DIM 65
#define MLP_W 64
#define NBATCH 4
#define D3 2304               // (ORDER+1)*D_MODEL
#define ROWS (NBATCH*MAX_LEN) // 16384

typedef unsigned short u16;
typedef unsigned int u32;
typedef float f4 __attribute__((ext_vector_type(4)));
typedef __bf16 bf16x8 __attribute__((ext_vector_type(8)));
typedef float f32x4 __attribute__((ext_vector_type(4)));

__device__ inline u16 f2bf(float x) {
    u32 u = __float_as_uint(x);
    u += 0x7fffu + ((u >> 16) & 1u);   // round-to-nearest-even
    return (u16)(u >> 16);
}
__device__ inline float bf2f(u16 v) { return __uint_as_float((u32)v << 16); }
__device__ inline u32 pk2(float a, float b) {
    return (u32)f2bf(a) | ((u32)f2bf(b) << 16);
}

// direct global->LDS async copy, 16B per lane; lds base must be wave-uniform.
// One call moves 64 lanes x 16B = 1KB, landing at ldsbase + lane*16B.
#define GLDS16(gp, lp) __builtin_amdgcn_global_load_lds( \
    (const __attribute__((address_space(1))) u32*)(gp), \
    (__attribute__((address_space(3))) u32*)(lp), 16, 0, 0)

// ---------------------------------------------------------------------------
// K1a: 3-layer sin-MLP -> k3 (MAX_LEN x 64 fp32).
// ---------------------------------------------------------------------------
__launch_bounds__(256)
__global__ void filter_mlp_kernel(const float* __restrict__ z,
                                  const float* __restrict__ fin_W,
                                  const float* __restrict__ fin_b,
                                  const float* __restrict__ freq,
                                  const float* __restrict__ mid_W,
                                  const float* __restrict__ mid_b,
                                  float* __restrict__ k3out)
{
    __shared__ __align__(16) float W1[PE_DIM*MLP_W];    // 16.6 KB
    __shared__ __align__(16) float Wm[2*MLP_W*MLP_W];   // 32 KB
    __shared__ __align__(16) float zs[16*PE_DIM];       // 4.2 KB
    __shared__ __align__(16) float kb[2][16*MLP_W];     // 8 KB
    int tid = threadIdx.x;
    int t0 = blockIdx.x * 16;
    for (int i = tid; i < PE_DIM*MLP_W; i += 256) W1[i] = fin_W[i];
    for (int i = tid; i < 2*MLP_W*MLP_W; i += 256) Wm[i] = mid_W[i];
    for (int i = tid; i < 16*PE_DIM; i += 256) zs[i] = z[(size_t)t0*PE_DIM + i];
    __syncthreads();

    int j = tid & 63, tl = tid >> 6;   // j: output unit, tl: 0..3 (t = tl+4*tt)
    float fj = freq[j];
    float a[4];

    // layer 1: z(65) -> 64, sin
    {
        float fb = fin_b[j];
        #pragma unroll
        for (int tt = 0; tt < 4; ++tt) a[tt] = fb;
        for (int i = 0; i < PE_DIM; ++i) {
            float w = W1[i*MLP_W + j];                   // coalesced
            #pragma unroll
            for (int tt = 0; tt < 4; ++tt)
                a[tt] += zs[(tl + 4*tt)*PE_DIM + i] * w; // broadcast
        }
        #pragma unroll
        for (int tt = 0; tt < 4; ++tt)
            kb[0][(tl + 4*tt)*MLP_W + j] = sinf(fj*a[tt]);
    }
    __syncthreads();
    // layer 2
    {
        float mb = mid_b[j];
        #pragma unroll
        for (int tt = 0; tt < 4; ++tt) a[tt] = mb;
        for (int i = 0; i < MLP_W; ++i) {
            float w = Wm[i*MLP_W + j];
            #pragma unroll
            for (int tt = 0; tt < 4; ++tt)
                a[tt] += kb[0][(tl + 4*tt)*MLP_W + i] * w;
        }
        #pragma unroll
        for (int tt = 0; tt < 4; ++tt)
            kb[1][(tl + 4*tt)*MLP_W + j] = sinf(fj*a[tt]);
    }
    __syncthreads();
    // layer 3 -> global k3
    {
        float mb = mid_b[MLP_W + j];
        #pragma unroll
        for (int tt = 0; tt < 4; ++tt) a[tt] = mb;
        for (int i = 0; i < MLP_W; ++i) {
            float w = Wm[MLP_W*MLP_W + i*MLP_W + j];
            #pragma unroll
            for (int tt = 0; tt < 4; ++tt)
                a[tt] += kb[1][(tl + 4*tt)*MLP_W + i] * w;
        }
        #pragma unroll
        for (int tt = 0; tt < 4; ++tt)
            k3out[(size_t)(t0 + tl + 4*tt)*MLP_W + j] = sinf(fj*a[tt]); // coalesced
    }
}

// ---------------------------------------------------------------------------
// K1b: hTt[t,d] = (k3[t,:] @ fout_W[:,d]) * decay(t,d).
// ---------------------------------------------------------------------------
__launch_bounds__(256)
__global__ void filter_out_kernel(const float* __restrict__ k3,
                                  const float* __restrict__ fout_W,
                                  float* __restrict__ hTt)
{
    __shared__ __align__(16) float ks[64*64];    // [t][i] 16 KB
    __shared__ __align__(16) float fs[64*132];   // [i][d] padded, 33.8 KB
    int tid = threadIdx.x;
    int d0 = blockIdx.x * 128;
    int t0 = blockIdx.y * 64;

    for (int q = tid; q < 1024; q += 256)        // 4096 floats of k3 tile
        *(f4*)&ks[q*4] = *(const f4*)&k3[(size_t)t0*MLP_W + q*4];
    for (int q = tid; q < 2048; q += 256) {      // 64 rows x 32 f4 of fout tile
        int i = q >> 5, c = q & 31;
        *(f4*)&fs[i*132 + c*4] = *(const f4*)&fout_W[(size_t)i*D_MODEL + d0 + c*4];
    }
    __syncthreads();

    int c = tid & 31;            // d sub-block: d = d0 + 4c + dd
    int t_base = (tid >> 5)*8;   // 8 t per thread
    f4 acc[8];
    #pragma unroll
    for (int tt = 0; tt < 8; ++tt) acc[tt] = (f4){0.f,0.f,0.f,0.f};

    for (int i = 0; i < MLP_W; ++i) {
        f4 fv = *(const f4*)&fs[i*132 + c*4];
        #pragma unroll
        for (int tt = 0; tt < 8; ++tt) {
            float kv = ks[(t_base + tt)*MLP_W + i];   // 2-way broadcast per wave
            acc[tt][0] += kv * fv[0];
            acc[tt][1] += kv * fv[1];
            acc[tt][2] += kv * fv[2];
            acc[tt][3] += kv * fv[3];
        }
    }

    const float MIND = -3.0701134573253944f;   // ln(0.01)/1.5
    const float MAXD = -15.350567286626972f;   // ln(0.01)/0.3
    #pragma unroll
    for (int tt = 0; tt < 8; ++tt) {
        int t = t0 + t_base + tt;
        float ttf = (float)t * (1.0f/(float)(MAX_LEN-1));
        f4 o;
        #pragma unroll
        for (int dd = 0; dd < 4; ++dd) {
            int d = d0 + 4*c + dd;
            float delta = MIND + (MAXD-MIND)*((float)d*(1.0f/(float)(D_MODEL-1)));
            o[dd] = acc[tt][dd] * expf(-ttf*fabsf(delta));
        }
        *(f4*)&hTt[(size_t)t*D_MODEL + d0 + 4*c] = o;   // coalesced f4
    }
}

// ---------------------------------------------------------------------------
// cast fp32 -> bf16 (elementwise, 8/thread)
// ---------------------------------------------------------------------------
__global__ void cast_bf16_kernel(const float* __restrict__ src,
                                 u16* __restrict__ dst, int n)
{
    int i = (blockIdx.x*256 + threadIdx.x)*8;
    if (i + 7 >= n) {
        for (int j = i; j < n; ++j) dst[j] = f2bf(src[j]);
        return;
    }
    float4 a = *(const float4*)(src + i);
    float4 b = *(const float4*)(src + i + 4);
    uint4 o;
    o.x = pk2(a.x, a.y);
    o.y = pk2(a.z, a.w);
    o.z = pk2(b.x, b.y);
    o.w = pk2(b.z, b.w);
    *(uint4*)(dst + i) = o;
}

// ---------------------------------------------------------------------------
// transpose + cast: src (R x C fp32) -> dst (C x R bf16)
// ---------------------------------------------------------------------------
__global__ void transpose_cast_kernel(const float* __restrict__ src,
                                      u16* __restrict__ dst, int R, int C)
{
    __shared__ u16 tile[64][65];
    int c0 = blockIdx.x*64, r0 = blockIdx.y*64;
    int tid = threadIdx.x;
    #pragma unroll
    for (int p = 0; p < 16; ++p) {
        int idx = tid + 256*p;
        int rr = idx >> 6, cc = idx & 63;
        tile[rr][cc] = f2bf(src[(size_t)(r0+rr)*C + c0 + cc]);
    }
    __syncthreads();
    #pragma unroll
    for (int p = 0; p < 16; ++p) {
        int idx = tid + 256*p;
        int cr = idx >> 6, rc = idx & 63;
        dst[(size_t)(c0+cr)*R + r0 + rc] = tile[rc][cr];
    }
}

// ---------------------------------------------------------------------------
// K2/K6: C[M,N] = A[M,K]bf16 @ Bt[N,K]bf16 + bias
// m97 structure: 128x128 tile, BK=32, global_load_lds width=16, unpadded
// 32-u16 LDS rows, 2 barriers/iter, 4x4 MFMA 16x16x32 per wave.
// ---------------------------------------------------------------------------
__launch_bounds__(256)
__global__ void gemm_mfma_kernel(const u16* __restrict__ A,   // M x K
                                 const u16* __restrict__ Bt,  // N x K
                                 const float* __restrict__ bias,
                                 float* __restrict__ C,
                                 int M, int N, int K)
{
    __shared__ __align__(16) u16 As[128*32];
    __shared__ __align__(16) u16 Bs[128*32];
    int tid = threadIdx.x;
    int lane = tid & 63, w = tid >> 6;
    int wm = (w >> 1)*64, wn = (w & 1)*64;
    int lrow = lane & 15, lch = lane >> 4;
    int m0 = blockIdx.y * 128, n0 = blockIdx.x * 128;

    int srow = lane >> 2;          // 0..15
    int scol = (lane & 3)*8;
    const u16* Ag = A  + (size_t)(m0 + w*32 + srow)*K + scol;
    const u16* Bg = Bt + (size_t)(n0 + w*32 + srow)*K + scol;
    u16* AsW = As + w*1024;   // wave-uniform
    u16* BsW = Bs + w*1024;

    f32x4 acc[4][4];
    #pragma unroll
    for (int i = 0; i < 4; ++i)
        #pragma unroll
        for (int j = 0; j < 4; ++j)
            acc[i][j] = (f32x4){0.f,0.f,0.f,0.f};

    for (int k0 = 0; k0 < K; k0 += 32) {
        GLDS16(Ag + k0,            AsW);
        GLDS16(Ag + 16*(size_t)K + k0, AsW + 512);
        GLDS16(Bg + k0,            BsW);
        GLDS16(Bg + 16*(size_t)K + k0, BsW + 512);
        __syncthreads();               // drains vmcnt(0): tile visible
        bf16x8 af[4], bfr[4];
        #pragma unroll
        for (int i = 0; i < 4; ++i) {
            af[i]  = *(const bf16x8*)&As[(wm + i*16 + lrow)*32 + lch*8];
            bfr[i] = *(const bf16x8*)&Bs[(wn + i*16 + lrow)*32 + lch*8];
        }
        #pragma unroll
        for (int mt = 0; mt < 4; ++mt)
            #pragma unroll
            for (int nt = 0; nt < 4; ++nt)
                acc[mt][nt] = __builtin_amdgcn_mfma_f32_16x16x32_bf16(
                    af[mt], bfr[nt], acc[mt][nt], 0, 0, 0);
        __syncthreads();               // reads done before next overwrite
    }
    #pragma unroll
    for (int nt = 0; nt < 4; ++nt) {
        int n = n0 + wn + nt*16 + lrow;
        float bv = bias[n];
        #pragma unroll
        for (int mt = 0; mt < 4; ++mt) {
            int m = m0 + wm + mt*16 + lch*4;
            #pragma unroll
            for (int r = 0; r < 4; ++r)
                C[(size_t)(m + r)*N + n] = acc[mt][nt][r] + bv;
        }
    }
}

// ---------------------------------------------------------------------------
// K3: short conv (width 3, causal) + split; seq=x0*v -> bf16 (B,768,L),
// gate=x1 -> fp32 (B*L,768)
// ---------------------------------------------------------------------------
__global__ void convprep_kernel(const float* __restrict__ up,
                                const float* __restrict__ conv_W,
                                const float* __restrict__ conv_b,
                                u16* __restrict__ seqbf,
                                float* __restrict__ gate)
{
    __shared__ float sb[64][65];
    int d0 = blockIdx.x * 64;
    int t0 = blockIdx.y * 64;
    int b  = blockIdx.z;
    int tid = threadIdx.x;
    #pragma unroll
    for (int i = 0; i < 16; ++i) {
        int idx = tid + 256*i;
        int trow = idx >> 6, dcol = idx & 63;
        int t = t0 + trow;
        int d = d0 + dcol;
        size_t r = ((size_t)b*MAX_LEN + t)*D3;
        float uc[3];
        #pragma unroll
        for (int g = 0; g < 3; ++g) {
            int c = d + g*D_MODEL;
            float u0 = up[r + c];
            float u1 = (t >= 1) ? up[r - D3 + c]   : 0.f;
            float u2 = (t >= 2) ? up[r - 2*D3 + c] : 0.f;
            uc[g] = conv_W[c]*u2 + conv_W[D3 + c]*u1 + conv_W[2*D3 + c]*u0 + conv_b[c];
        }
        sb[trow][dcol] = uc[0]*uc[2];
        gate[((size_t)b*MAX_LEN + t)*D_MODEL + d] = uc[1];
    }
    __syncthreads();
    #pragma unroll
    for (int i = 0; i < 16; ++i) {
        int idx = tid + 256*i;
        int drow = idx >> 6, tcol = idx & 63;
        seqbf[((size_t)b*D_MODEL + d0 + drow)*MAX_LEN + t0 + tcol] = f2bf(sb[tcol][drow]);
    }
}

// ---------------------------------------------------------------------------
// K4: long causal depthwise conv via block-Toeplitz MFMA.
// v3 (delta-factorized): ONE block per d; 4 waves = 4 batches.
// Identity: acc[g] += slab(r,s) * F(g-r, s), where the seq B-fragment F
// depends ONLY on (delta=g-r, s) -> 128 distinct B fragments per wave.
// New loop: for s { build ALL 16 round-slabs at segment s (same total build
// cost as round-pair version); hold them in 16 VGPR frags; for delta=0..15
// read F(delta,s) ONCE and apply to all 16-delta rounds }.
// LDS b128 reads/wave: 704 -> 256 (B: 576->128, A: 128). MFMA count
// unchanged (1088/wave). Barriers unchanged (2 per s).
// Build reads: 4 slab-groups/wave hit hp at 512B stride (same bank set);
// per-group kk-rotation (+4 per group) staggers banks -> conflict-free.
// ---------------------------------------------------------------------------
__launch_bounds__(256)
__global__ void longconv_mfma_kernel(const u16* __restrict__ seqbf, // (B,768,L) bf16
                                     const u16* __restrict__ hbf,   // (768,L) bf16
                                     const float* __restrict__ filt_bias,
                                     float* __restrict__ yT)        // (B,768,L) fp32
{
    __shared__ __align__(16) u16 sq[4*4896];   // per-batch swizzled seq, 256-elem zero pad below
    __shared__ __align__(16) u16 hp[4112];     // bf16 h, 16-elem zero pad below
    __shared__ __align__(16) u16 A_s[16*648];  // 16 slabs = rounds 0..15 at segment s

    int d   = blockIdx.x;
    int tid = threadIdx.x;
    int lane = tid & 63, w = tid >> 6;         // w = batch
    int lrow = lane & 15, lch = lane >> 4;

    // stage seq for all 4 batches (9/8 swizzle expansion) + h (shared per d)
    for (int q = tid; q < 4*544; q += 256) {
        int b = q / 544, qq = q - b*544;       // 32 pad quads + 512 data per batch
        int p = b*4896 + ((qq + (qq >> 3)) << 3);
        uint4 o = make_uint4(0u,0u,0u,0u);
        if (qq >= 32) o = *(const uint4*)&seqbf[((size_t)b*D_MODEL + d)*MAX_LEN + (size_t)(qq-32)*8];
        *(uint4*)&sq[p] = o;
    }
    for (int q = tid; q < 514; q += 256) {     // 2 pad quads + 512 data
        uint4 o = make_uint4(0u,0u,0u,0u);
        if (q >= 2) o = *(const uint4*)&hbf[(size_t)d*MAX_LEN + (size_t)(q-2)*8];
        *(uint4*)&hp[q*8] = o;
    }

    f32x4 acc[16];
    #pragma unroll
    for (int g = 0; g < 16; ++g) acc[g] = (f32x4){0.f,0.f,0.f,0.f};

    // slab build: thread -> (round slab_b, row i_b); 16 threads per slab
    int slab_b = tid >> 4;                     // 0..15 = round r
    int i_b    = tid & 15;
    int rot    = (slab_b & 3)*4;               // bank-stagger for the 4 groups/wave
    u32* bld = (u32*)&A_s[slab_b*648 + i_b*40];

    const char* sqb = (const char*)(sq + w*4896);   // per-wave (batch) base
    int Q0 = 30 + 2*lrow + lch;                     // = (240+16lrow+8lch)/8

#define MM(af_, bf_, gi) acc[gi] = __builtin_amdgcn_mfma_f32_16x16x32_bf16(af_, bf_, acc[gi], 0, 0, 0)

    #pragma unroll 1
    for (int s = 0; s < 8; ++s) {
        __syncthreads();   // prior segment's A_s reads done (and staging on s=0)
        {   // build 16 slabs: A(r)[i][k] = hp[32 + 256r + 32s + i - k], k=0..31
            int hbase = 32 + 256*slab_b + 32*s + i_b;
            #pragma unroll
            for (int j = 0; j < 16; ++j) {
                int kk = (j + rot) & 15;
                u16 v0 = hp[hbase - 2*kk];
                u16 v1 = hp[hbase - 2*kk - 1];
                bld[kk] = (u32)v0 | ((u32)v1 << 16);
            }
        }
        __syncthreads();
        bf16x8 aR[16];
        #pragma unroll
        for (int r = 0; r < 16; ++r)
            aR[r] = *(const bf16x8*)&A_s[r*648 + lrow*40 + lch*8];
        int Qs = Q0 - 4*s;                              // >= 2, no negatives
        const char* bp = sqb + (Qs*16 + (Qs >> 3)*16);  // swizzled base
        #pragma unroll
        for (int dlt = 0; dlt < 16; ++dlt) {
            bf16x8 F = *(const bf16x8*)(bp + 576*dlt);  // exact through swizzle
            #pragma unroll
            for (int r = 0; r < 16 - dlt; ++r)
                MM(aR[r], F, r + dlt);
        }
    }
#undef MM

    // epilogue: y = acc + filt_bias[d]*seq ; write fp32 to yT
    float fb = filt_bias[d];
    const u16* sqbu = sq + w*4896;
    float* dsty = yT + ((size_t)w*D_MODEL + d)*MAX_LEN;
    #pragma unroll
    for (int g = 0; g < 16; ++g) {
        int t0 = 256*g + 16*lrow + 4*lch;
        int elem = 256 + t0;                 // multiple of 4; 4 elems in one quad
        int Q = elem >> 3;
        const u16* pv = &sqbu[(((Q + (Q >> 3)) << 3)) | (elem & 7)];
        ushort4 sv = *(const ushort4*)pv;    // 8B aligned
        f4 o;
        o[0] = acc[g][0] + fb*bf2f(sv.x);
        o[1] = acc[g][1] + fb*bf2f(sv.y);
        o[2] = acc[g][2] + fb*bf2f(sv.z);
        o[3] = acc[g][3] + fb*bf2f(sv.w);
        *(f4*)&dsty[t0] = o;
    }
}

// ---------------------------------------------------------------------------
// K5: Afin(bf16)[b*L+t, d] = yT[b,d,t] * gate[b*L+t, d]
// ---------------------------------------------------------------------------
__global__ void gatemul_kernel(const float* __restrict__ yT,
                               const float* __restrict__ gate,
                               u16* __restrict__ Afin)
{
    __shared__ float tb[64][65];
    int d0 = blockIdx.x * 64;
    int t0 = blockIdx.y * 64;
    int b  = blockIdx.z;
    int tid = threadIdx.x;
    #pragma unroll
    for (int i = 0; i < 16; ++i) {
        int idx = tid + 256*i;
        int drow = idx >> 6, tcol = idx & 63;
        tb[drow][tcol] = yT[((size_t)b*D_MODEL + d0 + drow)*MAX_LEN + t0 + tcol];
    }
    __syncthreads();
    #pragma unroll
    for (int i = 0; i < 16; ++i) {
        int idx = tid + 256*i;
        int trow = idx >> 6, dcol = idx & 63;
        size_t r = ((size_t)b*MAX_LEN + t0 + trow)*D_MODEL + d0 + dcol;
        Afin[r] = f2bf(tb[dcol][trow] * gate[r]);
    }
}

// ---------------------------------------------------------------------------
extern "C" void kernel_launch(void* const* d_in, const int* in_sizes, int n_in,
                              void* d_out, int out_size, void* d_ws, size_t ws_size,
                              hipStream_t stream)
{
    (void)in_sizes; (void)n_in; (void)out_size; (void)ws_size;
    const float* u      = (const float*)d_in[0];
    const float* z      = (const float*)d_in[1];
    const float* fin_W  = (const float*)d_in[2];
    const float* fin_b  = (const float*)d_in[3];
    const float* freq   = (const float*)d_in[4];
    const float* mid_W  = (const float*)d_in[5];
    const float* mid_b  = (const float*)d_in[6];
    const float* fout_W = (const float*)d_in[7];
    const float* proj_W = (const float*)d_in[8];
    const float* proj_b = (const float*)d_in[9];
    const float* conv_W = (const float*)d_in[10];
    const float* conv_b = (const float*)d_in[11];
    const float* fbias  = (const float*)d_in[12];
    const float* out_W  = (const float*)d_in[13];
    const float* out_b  = (const float*)d_in[14];
    float* out = (float*)d_out;

    // ws layout (floats), total 65,667,072 f = 262.7 MB:
    float* ws    = (float*)d_ws;
    u16*   hbf   = (u16*)ws;                          // 3,145,728 u16 = 1,572,864 f
    float* up    = ws + 1572864;                      // 37,748,736 f
    float* gate  = up + 37748736;                     // 12,582,912 f
    u16*   seqbf = (u16*)(gate + 12582912);           // 12,582,912 u16 = 6,291,456 f
    u16*   Abf   = (u16*)(gate + 12582912 + 6291456); // 12,582,912 u16 = 6,291,456 f
    u16*   BpT1  = (u16*)(gate + 12582912 + 2*6291456);          // 884,736 f
    u16*   BpT2  = (u16*)(gate + 12582912 + 2*6291456 + 884736); // 294,912 f
    // aliases in regions dead at time of use:
    float* hTt   = up;                    // t-major h; dead before GEMM1 writes up
    float* yT    = up;                    // longconv out; up fp32 dead after convprep
    u16*   Afinbf= (u16*)(up + 16777216); // gatemul out; disjoint from yT (12.58M f)
    float* k3buf = gate;                  // 1 MB; gate region dead until convprep

    filter_mlp_kernel<<<MAX_LEN/16, 256, 0, stream>>>(z, fin_W, fin_b, freq,
                                                      mid_W, mid_b, k3buf);
    filter_out_kernel<<<dim3(D_MODEL/128, MAX_LEN/64), 256, 0, stream>>>(
        k3buf, fout_W, hTt);
    transpose_cast_kernel<<<dim3(D_MODEL/64, MAX_LEN/64), 256, 0, stream>>>(
        hTt, hbf, MAX_LEN, D_MODEL);
    cast_bf16_kernel<<<(ROWS*D_MODEL)/(256*8), 256, 0, stream>>>(u, Abf, ROWS*D_MODEL);
    transpose_cast_kernel<<<dim3(D3/64, D_MODEL/64), 256, 0, stream>>>(
        proj_W, BpT1, D_MODEL, D3);
    gemm_mfma_kernel<<<dim3(D3/128, ROWS/128), 256, 0, stream>>>(
        Abf, BpT1, proj_b, up, ROWS, D3, D_MODEL);
    convprep_kernel<<<dim3(D_MODEL/64, MAX_LEN/64, NBATCH), 256, 0, stream>>>(
        up, conv_W, conv_b, seqbf, gate);
    transpose_cast_kernel<<<dim3(D_MODEL/64, D_MODEL/64), 256, 0, stream>>>(
        out_W, BpT2, D_MODEL, D_MODEL);
    longconv_mfma_kernel<<<D_MODEL, 256, 0, stream>>>(seqbf, hbf, fbias, yT);
    gatemul_kernel<<<dim3(D_MODEL/64, MAX_LEN/64, NBATCH), 256, 0, stream>>>(
        yT, gate, Afinbf);
    gemm_mfma_kernel<<<dim3(D_MODEL/128, ROWS/128), 256, 0, stream>>>(
        Afinbf, BpT2, out_b, out, ROWS, D_MODEL, D_MODEL);
}